// Round 2
// baseline (369.478 us; speedup 1.0000x reference)
//
#include <hip/hip_runtime.h>

// Problem: B=16, T=8192, C=512, Y=256. pool_by_durations (mean over spans).
// Strategy: 3 kernels, all streaming/balanced:
//   K1 init_scan  : zero ws_sum (8 MiB) + per-batch inclusive scan of durations
//   K2 accumulate : grid (T/64, B); each block streams 64 contiguous frames
//                   (128 KiB), walks the spans covering its chunk, flushes
//                   partial span sums to ws_sum via atomicAdd (<=2-3 blocks/span)
//   K3 finalize   : out = cnt>0 ? sum/cnt : 0   (also covers poisoned d_out)
// ws layout: [0,8MiB) float sum[B][Y][C]; then int cum[B][Y]; int cnt[B][Y].

#define BB 16
#define TT 8192
#define CC 512
#define YY 256
#define C4 128          // float4 per frame
#define FPB 64          // frames per accumulate block
#define NCHUNK (TT / FPB)

__global__ __launch_bounds__(256) void init_scan_kernel(
    float4* __restrict__ sum4, const int* __restrict__ dur,
    int* __restrict__ cum, int* __restrict__ cnt)
{
    const int tid = threadIdx.x;
    const size_t i = (size_t)blockIdx.x * 256 + tid;   // 2048*256 = 512K float4 = 8 MiB
    sum4[i] = make_float4(0.f, 0.f, 0.f, 0.f);

    if (blockIdx.x < BB) {                              // block-uniform branch
        const int b = blockIdx.x;
        __shared__ int sc[YY];
        const int d = dur[b * YY + tid];
        sc[tid] = d;
        for (int off = 1; off < YY; off <<= 1) {        // Hillis-Steele inclusive scan
            __syncthreads();
            const int add = (tid >= off) ? sc[tid - off] : 0;
            __syncthreads();
            sc[tid] += add;
        }
        const int c  = sc[tid];                         // inclusive end
        const int s  = c - d;                           // start
        const int ec = (c < TT) ? c : TT;
        const int scl = (s < TT) ? s : TT;
        cum[b * YY + tid] = c;
        cnt[b * YY + tid] = ec - scl;                   // clamped frame count
    }
}

__global__ __launch_bounds__(256) void accumulate_kernel(
    const float4* __restrict__ emg4, const int* __restrict__ cum,
    float* __restrict__ sum)
{
    const int tid = threadIdx.x;
    const int b  = blockIdx.y;
    const int f0 = blockIdx.x * FPB;
    const int f1 = f0 + FPB;

    __shared__ int cum_s[YY];
    cum_s[tid] = cum[b * YY + tid];
    __syncthreads();

    // first span whose cumulative end exceeds f0 (uniform binary search)
    int lo_i = 0, hi_i = YY;
    while (lo_i < hi_i) {
        const int m = (lo_i + hi_i) >> 1;
        if (cum_s[m] <= f0) lo_i = m + 1; else hi_i = m;
    }
    int y = lo_i;

    const int c4 = tid & (C4 - 1);
    const int fo = tid >> 7;                            // frame parity
    const float4* src = emg4 + (size_t)b * TT * C4 + c4;
    __shared__ float4 red[C4];

    int lo = f0;
    while (y < YY && lo < f1) {                         // all block-uniform control
        int hi = cum_s[y]; if (hi > f1) hi = f1;        // slice [lo,hi) of span y

        float4 acc = make_float4(0.f, 0.f, 0.f, 0.f);
        #pragma unroll 4
        for (int t = lo + fo; t < hi; t += 2) {
            const float4 x = src[(size_t)t * C4];
            acc.x += x.x; acc.y += x.y; acc.z += x.z; acc.w += x.w;
        }

        __syncthreads();                                // red reuse barrier
        if (fo == 1) red[c4] = acc;
        __syncthreads();
        if (fo == 0) {
            const float4 r = red[c4];
            float* dst = sum + ((size_t)(b * YY + y)) * CC + c4 * 4;
            atomicAdd(dst + 0, acc.x + r.x);
            atomicAdd(dst + 1, acc.y + r.y);
            atomicAdd(dst + 2, acc.z + r.z);
            atomicAdd(dst + 3, acc.w + r.w);
        }

        lo = hi;
        y++;
        while (y < YY && cum_s[y] <= lo) y++;           // skip empty spans
    }
}

__global__ __launch_bounds__(256) void finalize_kernel(
    const float4* __restrict__ sum4, const int* __restrict__ cnt,
    float4* __restrict__ out4)
{
    const size_t i = (size_t)blockIdx.x * 256 + threadIdx.x;  // 512K float4
    const int by = (int)(i >> 7);                             // (b*Y+y)
    const int c  = cnt[by];
    const float4 s = sum4[i];
    float4 o = make_float4(0.f, 0.f, 0.f, 0.f);
    if (c > 0) {
        const float inv = 1.0f / (float)c;
        o.x = s.x * inv; o.y = s.y * inv; o.z = s.z * inv; o.w = s.w * inv;
    }
    out4[i] = o;
}

extern "C" void kernel_launch(void* const* d_in, const int* in_sizes, int n_in,
                              void* d_out, int out_size, void* d_ws, size_t ws_size,
                              hipStream_t stream) {
    const float* emg = (const float*)d_in[0];    // (16, 8192, 512) fp32
    const int*   dur = (const int*)d_in[1];      // (16, 256) int32
    float*       out = (float*)d_out;            // (16, 256, 512) fp32

    float* ws_sum = (float*)d_ws;                               // 8 MiB
    int*   ws_cum = (int*)((char*)d_ws + ((size_t)8 << 20));    // 16 KiB
    int*   ws_cnt = ws_cum + BB * YY;                           // 16 KiB

    init_scan_kernel<<<2048, 256, 0, stream>>>((float4*)ws_sum, dur, ws_cum, ws_cnt);
    accumulate_kernel<<<dim3(NCHUNK, BB), 256, 0, stream>>>(
        (const float4*)emg, ws_cum, ws_sum);
    finalize_kernel<<<2048, 256, 0, stream>>>(
        (const float4*)ws_sum, ws_cnt, (float4*)out);
}

// Round 3
// 359.064 us; speedup vs baseline: 1.0290x; 1.0290x over previous
//
#include <hip/hip_runtime.h>

// Problem constants (match reference): B=16, T=8192, C=512, Y=256
#define BB 16
#define TT 8192
#define CC 512
#define YY 256
#define C4 128   // C/4 float4 lanes per frame

// One block per (b, y) phoneme span.  [R3: revert to R1 design — measured
// best. R2's balanced-streaming + atomics variant cost exactly its extra
// ~16 MB ws traffic (+8.6 us), proving this kernel is BW-bound at minimal
// traffic (~260 MB ~= 40 us at 6.7 TB/s).]
//   Phase 1: start = sum_{i<y} dur[b,i] via masked block reduction (durations
//            row is cache-hot across the 256 blocks of a batch).
//   Phase 2: mean-pool frames [start, end) clamped to [0,T]: 128 float4 lanes
//            cover C=512 (coalesced 2 KiB/frame), two frames in flight via
//            thread = (c4, frame_parity), pair-combined through LDS.
// Empty spans write exact zeros (also initializes poisoned d_out).
__global__ __launch_bounds__(256) void emg_pool_kernel(
    const float* __restrict__ emg,   // (B, T, C) fp32
    const int*   __restrict__ dur,   // (B, Y) int32
    float*       __restrict__ out)   // (B, Y, C) fp32
{
    const int y   = blockIdx.x;
    const int b   = blockIdx.y;
    const int tid = threadIdx.x;

    // ---- Phase 1: span bounds -------------------------------------------
    const int* drow = dur + b * YY;
    int v = (tid < y) ? drow[tid] : 0;           // masked: sum of dur[0..y-1]
    #pragma unroll
    for (int off = 32; off > 0; off >>= 1) v += __shfl_down(v, off, 64);
    __shared__ int partial[4];
    if ((tid & 63) == 0) partial[tid >> 6] = v;
    __syncthreads();
    const int s   = partial[0] + partial[1] + partial[2] + partial[3];
    const int e   = s + drow[y];
    const int sc  = (s < TT) ? s : TT;           // s >= 0 always (dur >= 0)
    const int ec  = (e < TT) ? e : TT;
    const int cnt = ec - sc;                     // frames in span (>= 0)

    // ---- Phase 2: pooled mean -------------------------------------------
    const int c4 = tid & (C4 - 1);               // which float4 of the frame
    const int fo = tid >> 7;                     // frame parity: 0 or 1
    const float4* src = (const float4*)emg + (size_t)b * TT * C4 + c4;

    float4 acc = make_float4(0.f, 0.f, 0.f, 0.f);
    #pragma unroll 4
    for (int t = sc + fo; t < ec; t += 2) {
        float4 x = src[(size_t)t * C4];
        acc.x += x.x; acc.y += x.y; acc.z += x.z; acc.w += x.w;
    }

    __shared__ float4 red[C4];                   // 2 KiB pair-combine buffer
    if (fo == 1) red[c4] = acc;
    __syncthreads();
    if (fo == 0) {
        float4 o = make_float4(0.f, 0.f, 0.f, 0.f);
        if (cnt > 0) {
            const float inv = 1.0f / (float)cnt;
            const float4 r = red[c4];
            o.x = (acc.x + r.x) * inv;
            o.y = (acc.y + r.y) * inv;
            o.z = (acc.z + r.z) * inv;
            o.w = (acc.w + r.w) * inv;
        }
        ((float4*)out)[((size_t)b * YY + y) * C4 + c4] = o;
    }
}

extern "C" void kernel_launch(void* const* d_in, const int* in_sizes, int n_in,
                              void* d_out, int out_size, void* d_ws, size_t ws_size,
                              hipStream_t stream) {
    const float* emg = (const float*)d_in[0];    // (16, 8192, 512) fp32
    const int*   dur = (const int*)d_in[1];      // (16, 256) int32
    float*       out = (float*)d_out;            // (16, 256, 512) fp32

    dim3 grid(YY, BB);   // 256 x 16 = 4096 blocks
    emg_pool_kernel<<<grid, 256, 0, stream>>>(emg, dur, out);
}